// Round 9
// baseline (261.021 us; speedup 1.0000x reference)
//
#include <hip/hip_runtime.h>
#include <hip/hip_bf16.h>
#include <math.h>

// Problem constants
#define J   21
#define NH  7
#define H   4
#define HD  64
#define ALPHA 0.2f

// LDS strides (in elements)
#define HPS  264   // hp_bf row stride (shorts): k-contiguous (256+8 pad)
#define JPA  40    // attn_bf / x_bf row stride (shorts)
#define JPT  24    // h_t / h2_t row stride (shorts); j 21..23 zeroed; quad3 b128 reads overlap
                   // the next row (finite) — B-side (attn/attn2) k>=21 is exact zero so the
                   // products vanish; the very last h_t row spills into the zeroed tail pad.
#define F12S 24    // f1/f2 per-head stride (floats)

// LDS map (floats), total 7932 f = 31728 B:
//   [0,2904)      hp_bf[21+][HPS] shorts (s4 out / s5 A);
//                 attn2_bf @ short-off 96 = floats [48,400) (s7 out / s8 B... A)
//   [2904,4664)   attn_bf[4][22][JPA] shorts (s3 out / s4 B); x_bf bf16 overlay (s0 out / s1 A)
//   [4664,4856)   f1[4][F12S], f2[4][F12S] (s1b out / s3 in); f1o@4664, f2o@4688 overlay (s5 out / s7 in)
//   [4856,7928)   h_t[256][JPT] shorts (s1 out / s4 A); h2_t[64][JPT] overlay @ 6300 (s5 out / s8 B)
//   [7928,7932)   tail pad — zeroed in s0 (quad3 spillover of last h_t row)
#define LDS_FLOATS 7932

typedef __attribute__((ext_vector_type(8))) short short8;
typedef __attribute__((ext_vector_type(4))) float floatx4;

static __device__ __forceinline__ short f2bf(float f) {          // RNE (preconv only)
    __hip_bfloat16 h = __float2bfloat16(f);
    return __builtin_bit_cast(short, h);
}
static __device__ __forceinline__ short hi16(float f) {          // truncating bf16 (cheap)
    return (short)(__builtin_bit_cast(unsigned, f) >> 16);
}
static __device__ __forceinline__ unsigned pack2hi(float lo, float hi) {
    // D = [hi16(hi) : hi16(lo)] in one v_perm_b32
    return __builtin_amdgcn_perm(__builtin_bit_cast(unsigned, hi),
                                 __builtin_bit_cast(unsigned, lo), 0x07060302u);
}
static __device__ __forceinline__ float elu(float a) {
    return (a > 0.f) ? a : (__expf(a) - 1.f);
}

// ---- pre-kernel: bf16 weight tables + fused-dot tables ----
// ws shorts: [0,16384)      WoT[n=64][k=256] = bf(Wo[k][n])
//            [16384,18432)  WhT[(h*64+d)][8] : n<7 -> bf(Wh[h][n][d]), n=7 -> 0
//            [18432,18560)  wha[h][2][8] fp32 : wha[h][s][n] = sum_d Wh[h][n][d]*ah[h][s*64+d]
//            [18560,22656)  WoaT[s=16][k=256] : s<2 -> bf(sum_d Wo[k][d]*ao[s*64+d]), else 0
__global__ void preconv(const float* __restrict__ Wo, const float* __restrict__ Wh,
                        const float* __restrict__ ah, const float* __restrict__ ao,
                        short* __restrict__ ws) {
    int t = blockIdx.x * 256 + threadIdx.x;
    if (t < 16384) {
        int n = t >> 8, k = t & 255;
        ws[t] = f2bf(Wo[k * HD + n]);
    } else if (t < 18432) {
        int i = t - 16384;
        int hh = i >> 9, d = (i >> 3) & 63, n = i & 7;
        ws[t] = (n < 7) ? f2bf(Wh[(hh * NH + n) * HD + d]) : (short)0;
    } else if (t < 18496) {
        int i = t - 18432;                 // 0..63
        int hh = i >> 4, s = (i >> 3) & 1, n = i & 7;
        float acc = 0.f;
        if (n < 7) {
            for (int d = 0; d < HD; d++)
                acc += Wh[(hh * NH + n) * HD + d] * ah[hh * 2 * HD + s * HD + d];
        }
        ((float*)(ws + 18432))[i] = acc;
    } else if (t < 22592) {
        int i = t - 18496;                 // 0..4095
        int s = i >> 8, k = i & 255;
        short v = 0;
        if (s < 2) {
            float acc = 0.f;
            for (int d = 0; d < HD; d++)
                acc += Wo[k * HD + d] * ao[s * HD + d];
            v = f2bf(acc);
        }
        ws[18560 + i] = v;
    }
}

__global__ __launch_bounds__(256, 4)
void gat_kernel(const float* __restrict__ inp,
                const short* __restrict__ ws,   // WoT + WhT + wha + WoaT
                float* __restrict__ out)
{
    __shared__ __align__(16) float smem[LDS_FLOATS];
    short* hp_bf    = (short*)smem;                 // [21+][HPS]
    short* attn2_bf = (short*)smem + 96;            // [21+][32] floats [48,400)
    short* attn_bf  = (short*)(smem + 2904);        // [4][22][JPA] (row 21/head unused)
    short* x_bf     = (short*)(smem + 2904);        // [22][JPA] overlay
    float* f1       = smem + 4664;                  // [4][F12S]
    float* f2       = smem + 4760;
    float* f1o      = smem + 4664;                  // overlay (f1/f2 dead post-s3)
    float* f2o      = smem + 4688;
    short* h_t      = (short*)(smem + 4856);        // [256][JPT]
    short* h2_t     = (short*)(smem + 6300);        // [64][JPT] (overlays dead h_t)

    const short* WoT  = ws;
    const short* WhT  = ws + 16384;
    const float* whaF = (const float*)(ws + 18432);
    const short* WoaT = ws + 18560;

    const int t    = threadIdx.x;
    const int w    = t >> 6;          // wave = head = tile index
    const int lane = t & 63;
    const int quad = lane >> 4;
    const int col  = lane & 15;
    const int rc   = (16 + col < 21) ? (16 + col) : 20;   // clamped M1 row (garbage masked)

    const size_t pair = blockIdx.x;
    const float* ip = inp + pair * (size_t)(J * NH);

    // ---- stage 0 (single pass): x_bf full rows (values + zero pads) as b64; zero tail ----
    if (t < 220) {
        int row = t / 10, c4 = t - row * 10;
        unsigned lo = 0, hi = 0;
        if (row < 21) {
            if (c4 == 0) {
                float v0 = ip[row*3+0], v1 = ip[row*3+1], v2 = ip[row*3+2];
                float v3 = ip[63+row*3+0];
                lo = pack2hi(v0, v1); hi = pack2hi(v2, v3);
            } else if (c4 == 1) {
                float v4 = ip[63+row*3+1], v5 = ip[63+row*3+2], v6 = ip[126+row];
                lo = pack2hi(v4, v5); hi = pack2hi(v6, 0.f);
            }
        }
        *(uint2*)(x_bf + row * JPA + c4 * 4) = make_uint2(lo, hi);
    } else if (t < 224) {
        smem[7928 + (t - 220)] = 0.f;   // tail pad: s4 quad3 A-read of last h_t row spills here
    }
    __syncthreads();

    // ---- stage 1 (MFMA): h = x[21x7pad32] @ Wh_head[7x64] -> h_t bf16 (B-layout, b64-packed);
    //      1b: f1/f2 = x @ wha (fp32, straight from global — L1-hot) ----
    {
        short8 xa0 = *(const short8*)(x_bf + col * JPA + quad * 8);
        short8 xa1 = *(const short8*)(x_bf + rc  * JPA + quad * 8);
        #pragma unroll
        for (int nt = 0; nt < 4; nt++) {
            short8 b = *(const short8*)(WhT + ((w * 64 + nt * 16 + col) << 3) + quad * 8);
            floatx4 z = {0.f, 0.f, 0.f, 0.f};
            floatx4 c0 = __builtin_amdgcn_mfma_f32_16x16x32_bf16(xa0, b, z, 0, 0, 0);
            floatx4 c1 = __builtin_amdgcn_mfma_f32_16x16x32_bf16(xa1, b, z, 0, 0, 0);
            short* cb = h_t + (w * 64 + nt * 16 + col) * JPT;
            *(uint2*)(cb + quad * 4) =
                make_uint2(pack2hi(c0[0], c0[1]), pack2hi(c0[2], c0[3]));
            if (quad == 0)
                *(uint2*)(cb + 16) =
                    make_uint2(pack2hi(c1[0], c1[1]), pack2hi(c1[2], c1[3]));
            else if (quad == 1)
                *(uint2*)(cb + 20) = make_uint2(pack2hi(c1[0], 0.f), 0u);  // j=20 + zero pad 21..23
        }
        if (t < 84) {
            int hh = t / 21, j = t - hh * 21;
            float x0 = ip[j*3+0], x1 = ip[j*3+1], x2 = ip[j*3+2];
            float x3 = ip[63+j*3+0], x4 = ip[63+j*3+1], x5 = ip[63+j*3+2];
            float x6 = ip[126+j];
            const float* wp = whaF + hh * 16;
            f1[hh * F12S + j] = x0*wp[0] + x1*wp[1] + x2*wp[2] + x3*wp[3]
                              + x4*wp[4] + x5*wp[5] + x6*wp[6];
            f2[hh * F12S + j] = x0*wp[8] + x1*wp[9] + x2*wp[10] + x3*wp[11]
                              + x4*wp[12] + x5*wp[13] + x6*wp[14];
        }
    }
    __syncthreads();

    // ---- stage 3: attn rows = softmax_j( leaky_relu(f1[i]+f2[j]) ) -> bf16, k-pad zeroed.
    //      No max pass: |f1+f2| <~ 5 by weight-scale arithmetic -> exp is fp32-safe. ----
    if (t < 84) {
        int hh = t / 21, i = t - hh * 21;
        float fi = f1[hh * F12S + i];
        const float* f2r = f2 + hh * F12S;
        float ev[J];
        float ssum = 0.f;
        #pragma unroll
        for (int c4 = 0; c4 < 5; c4++) {
            float4 fv = ((const float4*)f2r)[c4];
            float e;
            e = fi + fv.x; e = (e >= 0.f) ? e : ALPHA * e; e = __expf(e); ev[c4*4+0] = e; ssum += e;
            e = fi + fv.y; e = (e >= 0.f) ? e : ALPHA * e; e = __expf(e); ev[c4*4+1] = e; ssum += e;
            e = fi + fv.z; e = (e >= 0.f) ? e : ALPHA * e; e = __expf(e); ev[c4*4+2] = e; ssum += e;
            e = fi + fv.w; e = (e >= 0.f) ? e : ALPHA * e; e = __expf(e); ev[c4*4+3] = e; ssum += e;
        }
        { float e = fi + f2r[20]; e = (e >= 0.f) ? e : ALPHA * e; e = __expf(e); ev[20] = e; ssum += e; }
        float inv = 1.f / ssum;
        unsigned* rowp = (unsigned*)(attn_bf + (hh * 22 + i) * JPA);
        #pragma unroll
        for (int k = 0; k < 10; k++)
            rowp[k] = pack2hi(ev[2*k] * inv, ev[2*k+1] * inv);
        rowp[10] = pack2hi(ev[20] * inv, 0.f);
        #pragma unroll
        for (int k = 11; k < 16; k++) rowp[k] = 0;     // k-pad: cancels h_t overlap garbage in s4
    }
    __syncthreads();

    // ---- stage 4 (MFMA, transposed): hp^T[d][m] = h_t(d-rows) @ attn^T, ELU ->
    //      packed b64 stores into hp_bf[m][k] (k-contiguous). m>=21 never written. ----
    {
        short8 bb0 = *(const short8*)(attn_bf + (w * 22 + col) * JPA + quad * 8);
        const int am  = 16 + col;
        const int amc = (am < 21) ? am : 20;          // clamped read; results masked below
        short8 bb1 = *(const short8*)(attn_bf + (w * 22 + amc) * JPA + quad * 8);
        #pragma unroll
        for (int dt = 0; dt < 4; dt++) {
            short8 a = *(const short8*)(h_t + (w * 64 + dt * 16 + col) * JPT + quad * 8);
            floatx4 z = {0.f, 0.f, 0.f, 0.f};
            floatx4 c0 = __builtin_amdgcn_mfma_f32_16x16x32_bf16(a, bb0, z, 0, 0, 0);
            floatx4 c1 = __builtin_amdgcn_mfma_f32_16x16x32_bf16(a, bb1, z, 0, 0, 0);
            *(uint2*)(hp_bf + col * HPS + w * 64 + dt * 16 + quad * 4) =
                make_uint2(pack2hi(elu(c0[0]), elu(c0[1])),
                           pack2hi(elu(c0[2]), elu(c0[3])));
            if (am < 21) {
                *(uint2*)(hp_bf + am * HPS + w * 64 + dt * 16 + quad * 4) =
                    make_uint2(pack2hi(elu(c1[0]), elu(c1[1])),
                               pack2hi(elu(c1[2]), elu(c1[3])));
            }
        }
    }
    __syncthreads();

    // ---- stage 5 (MFMA): h2 = hp[21x256] @ Wo[256x64] -> h2_t bf16 (b64-packed).
    //      ALL waves also accumulate the Woa f-tile in the same s-loop (reusing a0/a1;
    //      only +16 MFMA on the idle matrix pipe); wave 0 lanes col<2 store f1o/f2o. ----
    {
        floatx4 d0 = {0,0,0,0}, d1 = {0,0,0,0};
        floatx4 g0 = {0,0,0,0}, g1 = {0,0,0,0};
        #pragma unroll
        for (int s = 0; s < 8; s++) {
            short8 a0 = *(const short8*)(hp_bf + col * HPS + s * 32 + quad * 8);
            short8 a1 = *(const short8*)(hp_bf + rc  * HPS + s * 32 + quad * 8);
            short8 b  = *(const short8*)(WoT + (w * 16 + col) * 256 + s * 32 + quad * 8);
            short8 bg = *(const short8*)(WoaT + col * 256 + s * 32 + quad * 8);
            d0 = __builtin_amdgcn_mfma_f32_16x16x32_bf16(a0, b, d0, 0, 0, 0);
            d1 = __builtin_amdgcn_mfma_f32_16x16x32_bf16(a1, b, d1, 0, 0, 0);
            g0 = __builtin_amdgcn_mfma_f32_16x16x32_bf16(a0, bg, g0, 0, 0, 0);
            g1 = __builtin_amdgcn_mfma_f32_16x16x32_bf16(a1, bg, g1, 0, 0, 0);
        }
        const int c = w * 16 + col;
        short* cb = h2_t + c * JPT;
        *(uint2*)(cb + quad * 4) = make_uint2(pack2hi(d0[0], d0[1]), pack2hi(d0[2], d0[3]));
        if (quad == 0)
            *(uint2*)(cb + 16) = make_uint2(pack2hi(d1[0], d1[1]), pack2hi(d1[2], d1[3]));
        else if (quad == 1)
            *(uint2*)(cb + 20) = make_uint2(pack2hi(d1[0], 0.f), 0u);

        if (w == 0 && col < 2) {          // tiny store-only tail; compute was balanced
            float* fo = col ? f2o : f1o;
            #pragma unroll
            for (int r = 0; r < 4; r++) {
                fo[quad * 4 + r] = g0[r];
                int row1 = 16 + quad * 4 + r;
                if (row1 < J) fo[row1] = g1[r];
            }
        }
    }
    __syncthreads();

    // ---- stage 7: attn2 rows = softmax_j( leaky_relu(f1o[i]+f2o[j]) ) -> bf16 (no max pass) ----
    if (t < J) {
        float fi = f1o[t];
        float ev[J];
        float ssum = 0.f;
        #pragma unroll
        for (int c4 = 0; c4 < 5; c4++) {
            float4 fv = ((const float4*)f2o)[c4];
            float e;
            e = fi + fv.x; e = (e >= 0.f) ? e : ALPHA * e; e = __expf(e); ev[c4*4+0] = e; ssum += e;
            e = fi + fv.y; e = (e >= 0.f) ? e : ALPHA * e; e = __expf(e); ev[c4*4+1] = e; ssum += e;
            e = fi + fv.z; e = (e >= 0.f) ? e : ALPHA * e; e = __expf(e); ev[c4*4+2] = e; ssum += e;
            e = fi + fv.w; e = (e >= 0.f) ? e : ALPHA * e; e = __expf(e); ev[c4*4+3] = e; ssum += e;
        }
        { float e = fi + f2o[20]; e = (e >= 0.f) ? e : ALPHA * e; e = __expf(e); ev[20] = e; ssum += e; }
        float inv = 1.f / ssum;
        unsigned* rowp = (unsigned*)(attn2_bf + t * 32);
        #pragma unroll
        for (int k = 0; k < 10; k++)
            rowp[k] = pack2hi(ev[2*k] * inv, ev[2*k+1] * inv);
        rowp[10] = pack2hi(ev[20] * inv, 0.f);
        #pragma unroll
        for (int k = 11; k < 16; k++) rowp[k] = 0;     // k-pad: cancels h2_t overlap garbage in s8
    }
    __syncthreads();

    // ---- stage 8 (MFMA, barrier-free): hp2 = attn2[21x21pad32] @ h2[21x64], ELU,
    //      log-softmax over d entirely in-wave; waves pair-duplicate MFMAs, split rows ----
    {
        const int mt = w & 1;
        const int rh = w >> 1;
        const int arow = mt * 16 + col;
        const int ar = (arow < 21) ? arow : 20;            // clamped read; rows masked at store
        short8 a = *(const short8*)(attn2_bf + ar * 32 + quad * 8);
        floatx4 acc[4];
        #pragma unroll
        for (int nt = 0; nt < 4; nt++) {
            short8 b = *(const short8*)(h2_t + (nt * 16 + col) * JPT + quad * 8);
            floatx4 z = {0,0,0,0};
            acc[nt] = __builtin_amdgcn_mfma_f32_16x16x32_bf16(a, b, z, 0, 0, 0);
        }
        float* outp = out + pair * (size_t)(J * HD);
        #pragma unroll
        for (int rr = 0; rr < 2; rr++) {
            int r = rh * 2 + rr;
            int row = mt * 16 + quad * 4 + r;
            float v0 = elu(acc[0][r]), v1 = elu(acc[1][r]);
            float v2 = elu(acc[2][r]), v3 = elu(acc[3][r]);
            float s = __expf(v0) + __expf(v1) + __expf(v2) + __expf(v3);
            s += __shfl_xor(s, 1);
            s += __shfl_xor(s, 2);
            s += __shfl_xor(s, 4);
            s += __shfl_xor(s, 8);
            float ls = __logf(s);
            if (row < J) {
                outp[row * HD +      col] = v0 - ls;
                outp[row * HD + 16 + col] = v1 - ls;
                outp[row * HD + 32 + col] = v2 - ls;
                outp[row * HD + 48 + col] = v3 - ls;
            }
        }
    }
}

extern "C" void kernel_launch(void* const* d_in, const int* in_sizes, int n_in,
                              void* d_out, int out_size, void* d_ws, size_t ws_size,
                              hipStream_t stream) {
    const float* inp = (const float*)d_in[0];
    // d_in[1] = seq_start_end (int64) — unused by the reference computation
    const float* Wh  = (const float*)d_in[2];
    const float* ah  = (const float*)d_in[3];
    const float* Wo  = (const float*)d_in[4];
    const float* ao  = (const float*)d_in[5];
    float* outp = (float*)d_out;
    short* ws   = (short*)d_ws;   // 22656 shorts = 45312 B

    hipLaunchKernelGGL(preconv, dim3(89), dim3(256), 0, stream, Wo, Wh, ah, ao, ws);

    const int pairs = in_sizes[0] / (J * NH);  // 16384
    hipLaunchKernelGGL(gat_kernel, dim3(pairs), dim3(256), 0, stream,
                       inp, (const short*)ws, outp);
}

// Round 10
// 230.160 us; speedup vs baseline: 1.1341x; 1.1341x over previous
//
#include <hip/hip_runtime.h>
#include <hip/hip_bf16.h>
#include <math.h>

// Problem constants
#define J   21
#define NH  7
#define H   4
#define HD  64
#define ALPHA 0.2f

// LDS strides (in elements)
#define HPS  264   // hp_bf row stride (shorts)
#define JPA  40    // x_bf row stride (shorts)
#define JPT  24    // h_t / h2_t row stride (shorts); j 21..23 zeroed; quad3 b128 reads overlap
                   // the next row (finite) — A-side k>=21 is exact zero so products vanish;
                   // the very last h_t row spills into the zeroed tail pad.
#define F12S 24    // f1/f2 per-head stride (floats)
#define ROW2 68    // h2 fp32 row stride (floats)

// LDS map (floats), total 7932 f = 31728 B:
//   [0,2904)      hp_bf[22][HPS] shorts (s4 out / s5 A); xs_raw[147] overlay (s0/s1b);
//                 f1o@[0,21), f2o@[24,45) overlay post-s5 (s6 out / s8 in)
//   [2904,4664)   x_bf[22][JPA] shorts (s0 out / s1 A); dead after s1
//   [4664,4856)   f1[4][F12S] @4664, f2[4][F12S] @4760 (s1b out / s4 softmax in)
//   [4856,7928)   h_t[256][JPT] shorts (s1 out / s4 B); h2[21][ROW2] fp32 overlay (s5 out / s6 in);
//                 h2_t[64][JPT] shorts @ float-off 6300 (s5 out / s8 B)
//   [7928,7932)   tail pad — zeroed in s0 (quad3 spillover of last h_t row)
#define LDS_FLOATS 7932

typedef __attribute__((ext_vector_type(8))) short short8;
typedef __attribute__((ext_vector_type(4))) float floatx4;

static __device__ __forceinline__ short f2bf(float f) {          // RNE (preconv only)
    __hip_bfloat16 h = __float2bfloat16(f);
    return __builtin_bit_cast(short, h);
}
static __device__ __forceinline__ short hi16(float f) {          // truncating bf16 (cheap)
    return (short)(__builtin_bit_cast(unsigned, f) >> 16);
}
static __device__ __forceinline__ unsigned pack2hi(float lo, float hi) {
    return __builtin_amdgcn_perm(__builtin_bit_cast(unsigned, hi),
                                 __builtin_bit_cast(unsigned, lo), 0x07060302u);
}
static __device__ __forceinline__ float elu(float a) {
    return (a > 0.f) ? a : (__expf(a) - 1.f);
}

// ---- pre-kernel: bf16 weight tables + wha fusion (R7 version) ----
// ws shorts: [0,16384)      WoT[n=64][k=256] = bf(Wo[k][n])
//            [16384,18432)  WhT[(h*64+d)][8] : n<7 -> bf(Wh[h][n][d]), n=7 -> 0
//            [18432,18560)  wha[h][2][8] fp32 : wha[h][s][n] = sum_d Wh[h][n][d]*ah[h][s*64+d]
__global__ void preconv(const float* __restrict__ Wo, const float* __restrict__ Wh,
                        const float* __restrict__ ah, short* __restrict__ ws) {
    int t = blockIdx.x * 256 + threadIdx.x;
    if (t < 16384) {
        int n = t >> 8, k = t & 255;
        ws[t] = f2bf(Wo[k * HD + n]);
    } else if (t < 18432) {
        int i = t - 16384;
        int hh = i >> 9, d = (i >> 3) & 63, n = i & 7;
        ws[t] = (n < 7) ? f2bf(Wh[(hh * NH + n) * HD + d]) : (short)0;
    } else if (t < 18496) {
        int i = t - 18432;                 // 0..63
        int hh = i >> 4, s = (i >> 3) & 1, n = i & 7;
        float acc = 0.f;
        if (n < 7) {
            for (int d = 0; d < HD; d++)
                acc += Wh[(hh * NH + n) * HD + d] * ah[hh * 2 * HD + s * HD + d];
        }
        ((float*)(ws + 18432))[i] = acc;
    }
}

__global__ __launch_bounds__(256, 4)
void gat_kernel(const float* __restrict__ inp,
                const float* __restrict__ ao,   // (2*HD,)
                const short* __restrict__ ws,   // WoT + WhT + wha
                float* __restrict__ out)
{
    __shared__ __align__(16) float smem[LDS_FLOATS];
    short* hp_bf  = (short*)smem;                 // [22][HPS]
    float* f1o    = smem;                         // post-s5 overlays of hp region
    float* f2o    = smem + 24;
    float* f1     = smem + 4664;                  // [4][F12S]
    float* f2     = smem + 4760;
    short* h_t    = (short*)(smem + 4856);        // [256][JPT]
    float* h2     = smem + 4856;                  // [21][ROW2] fp32 (overlays dead h_t)
    short* h2_t   = (short*)(smem + 6300);        // [64][JPT] (overlays dead h_t)

    const short* WoT  = ws;
    const short* WhT  = ws + 16384;
    const float* whaF = (const float*)(ws + 18432);

    const int t    = threadIdx.x;
    const int w    = t >> 6;          // wave = head = tile index
    const int lane = t & 63;
    const int quad = lane >> 4;
    const int col  = lane & 15;
    const int rc   = (16 + col < 21) ? (16 + col) : 21;   // clamped M1 row (row 21 zeroed)

    const size_t pair = blockIdx.x;
    const float* ip = inp + pair * (size_t)(J * NH);

    // ---- stage 0: zero x_bf region + tail; scatter inputs (bf16 A-layout + raw fp32) ----
    for (int e = t; e < 440; e += 256) smem[2904 + e] = 0.f;
    if (t < 4) smem[7928 + t] = 0.f;   // tail pad: s4 quad3 B-read of last h_t row spills here
    __syncthreads();
    if (t < J * NH) {
        float v = ip[t];
        int j, k;
        if (t < 63)       { j = t / 3;        k = t % 3; }
        else if (t < 126) { j = (t - 63) / 3; k = 3 + (t - 63) % 3; }
        else              { j = t - 126;      k = 6; }
        ((short*)(smem + 2904))[j * JPA + k] = hi16(v);   // x_bf
        smem[t] = v;                                      // xs_raw (hp region, dead until s4)
    }
    __syncthreads();

    // ---- stage 1 (MFMA): h = x[21x7pad32] @ Wh_head[7x64] -> h_t bf16 (B-layout);
    //      1b: f1/f2 = x @ wha (fp32) ----
    {
        const short* x_bf = (const short*)(smem + 2904);
        short8 xa0 = *(const short8*)(x_bf + col * JPA + quad * 8);
        short8 xa1 = *(const short8*)(x_bf + rc  * JPA + quad * 8);
        #pragma unroll
        for (int nt = 0; nt < 4; nt++) {
            short8 b = *(const short8*)(WhT + ((w * 64 + nt * 16 + col) << 3) + quad * 8);
            floatx4 z = {0.f, 0.f, 0.f, 0.f};
            floatx4 c0 = __builtin_amdgcn_mfma_f32_16x16x32_bf16(xa0, b, z, 0, 0, 0);
            floatx4 c1 = __builtin_amdgcn_mfma_f32_16x16x32_bf16(xa1, b, z, 0, 0, 0);
            short* colbase = h_t + (w * 64 + nt * 16 + col) * JPT;
            #pragma unroll
            for (int r = 0; r < 4; r++) {
                colbase[quad * 4 + r] = hi16(c0[r]);
                int row1 = 16 + quad * 4 + r;
                if (row1 < J) colbase[row1] = hi16(c1[r]);
                else if (row1 < JPT) colbase[row1] = 0;
            }
        }
        if (t < 84) {
            int hh = t / 21, j = t - hh * 21;
            const float* xr = smem;    // xs_raw
            float x0 = xr[j*3+0], x1 = xr[j*3+1], x2 = xr[j*3+2];
            float x3 = xr[63+j*3+0], x4 = xr[63+j*3+1], x5 = xr[63+j*3+2];
            float x6 = xr[126+j];
            const float* wp = whaF + hh * 16;
            f1[hh * F12S + j] = x0*wp[0] + x1*wp[1] + x2*wp[2] + x3*wp[3]
                              + x4*wp[4] + x5*wp[5] + x6*wp[6];
            f2[hh * F12S + j] = x0*wp[8] + x1*wp[9] + x2*wp[10] + x3*wp[11]
                              + x4*wp[12] + x5*wp[13] + x6*wp[14];
        }
    }
    __syncthreads();

    // ---- stage 4 (MFMA + register softmax, NO s3 stage/barrier):
    //      each lane builds its attn A-frag window in registers:
    //      frag k-window = [quad*8, quad*8+8); row denominators via cross-quad butterfly.
    //      Then hp = attn[21x21pad32] @ h[21x64], ELU -> hp_bf (A-layout); hp row 21 zeroed. ----
    {
        // shared k-window of f2 (depends only on k): 2 x b128 broadcast-free reads
        float4 fqa = *(const float4*)(f2 + w * F12S + quad * 8);
        float4 fqb = *(const float4*)(f2 + w * F12S + quad * 8 + 4);
        float fq[8] = {fqa.x, fqa.y, fqa.z, fqa.w, fqb.x, fqb.y, fqb.z, fqb.w};
        float fi0 = f1[w * F12S + col];
        const int am  = 16 + col;
        const int amc = (am < 21) ? am : 20;          // duplicate row 20; results masked
        float fi1 = f1[w * F12S + amc];
        float e0[8], e1[8];
        float s0 = 0.f, s1 = 0.f;
        #pragma unroll
        for (int j = 0; j < 8; j++) {
            bool valid = (quad * 8 + j) < 21;
            float a0 = fi0 + fq[j]; a0 = (a0 >= 0.f) ? a0 : ALPHA * a0;
            float a1 = fi1 + fq[j]; a1 = (a1 >= 0.f) ? a1 : ALPHA * a1;
            float x0 = __expf(a0); x0 = valid ? x0 : 0.f;   // no max pass: |e| bounded small
            float x1 = __expf(a1); x1 = valid ? x1 : 0.f;
            e0[j] = x0; e1[j] = x1; s0 += x0; s1 += x1;
        }
        s0 += __shfl_xor(s0, 16); s0 += __shfl_xor(s0, 32);
        s1 += __shfl_xor(s1, 16); s1 += __shfl_xor(s1, 32);
        float inv0 = 1.f / s0, inv1 = 1.f / s1;
        short8 aa0, aa1;
        #pragma unroll
        for (int j = 0; j < 8; j++) {
            aa0[j] = hi16(e0[j] * inv0);
            aa1[j] = hi16(e1[j] * inv1);
        }

        #pragma unroll
        for (int nt = 0; nt < 4; nt++) {
            short8 b = *(const short8*)(h_t + (w * 64 + nt * 16 + col) * JPT + quad * 8);
            floatx4 z = {0.f, 0.f, 0.f, 0.f};
            floatx4 c0 = __builtin_amdgcn_mfma_f32_16x16x32_bf16(aa0, b, z, 0, 0, 0);
            floatx4 c1 = __builtin_amdgcn_mfma_f32_16x16x32_bf16(aa1, b, z, 0, 0, 0);
            #pragma unroll
            for (int r = 0; r < 4; r++) {
                int row0 = quad * 4 + r;
                hp_bf[row0 * HPS + w * 64 + nt * 16 + col] = hi16(elu(c0[r]));
                int row1 = 16 + quad * 4 + r;
                if (row1 < J)
                    hp_bf[row1 * HPS + w * 64 + nt * 16 + col] = hi16(elu(c1[r]));
                else if (row1 == 21)
                    hp_bf[21 * HPS + w * 64 + nt * 16 + col] = 0;
            }
        }
    }
    __syncthreads();

    // ---- stage 5 (MFMA): h2 = hp[21x256] @ Wo[256x64] -> h2 fp32 (s6) AND h2_t bf16 (s8) ----
    {
        floatx4 d0 = {0,0,0,0}, d1 = {0,0,0,0};
        #pragma unroll
        for (int s = 0; s < 8; s++) {
            short8 a0 = *(const short8*)(hp_bf + col * HPS + s * 32 + quad * 8);
            short8 a1 = *(const short8*)(hp_bf + rc  * HPS + s * 32 + quad * 8);
            short8 b  = *(const short8*)(WoT + (w * 16 + col) * 256 + s * 32 + quad * 8);
            d0 = __builtin_amdgcn_mfma_f32_16x16x32_bf16(a0, b, d0, 0, 0, 0);
            d1 = __builtin_amdgcn_mfma_f32_16x16x32_bf16(a1, b, d1, 0, 0, 0);
        }
        const int c = w * 16 + col;
        #pragma unroll
        for (int r = 0; r < 4; r++) {
            h2[(quad * 4 + r) * ROW2 + c] = d0[r];
            int row1 = 16 + quad * 4 + r;
            if (row1 < J) h2[row1 * ROW2 + c] = d1[r];
        }
        short* cb = h2_t + c * JPT;
        *(uint2*)(cb + quad * 4) = make_uint2(pack2hi(d0[0], d0[1]), pack2hi(d0[2], d0[3]));
        if (quad == 0)
            *(uint2*)(cb + 16) = make_uint2(pack2hi(d1[0], d1[1]), pack2hi(d1[2], d1[3]));
        else if (quad == 1)
            *(uint2*)(cb + 20) = make_uint2(pack2hi(d1[0], 0.f), 0u);
    }
    __syncthreads();

    // ---- stage 6: f1o[j] = h2[j][:].ao[:64], f2o[j] = h2[j][:].ao[64:] ----
    if (t < 2 * J) {
        int which = t / J, j = t % J;
        const float4* hrow = (const float4*)(h2 + j * ROW2);
        const float4* ap   = (const float4*)(ao + which * HD);
        float sacc = 0.f;
        #pragma unroll
        for (int k = 0; k < HD / 4; k++) {
            float4 hv = hrow[k], av = ap[k];
            sacc += hv.x*av.x + hv.y*av.y + hv.z*av.z + hv.w*av.w;
        }
        if (which == 0) f1o[j] = sacc; else f2o[j] = sacc;
    }
    __syncthreads();

    // ---- stage 8 (MFMA + register softmax, NO s7 stage/barrier, barrier-free):
    //      lane builds attn2 A-frag window in registers (row ar), then
    //      hp2 = attn2[21x21pad32] @ h2[21x64], ELU, in-wave log-softmax, store ----
    {
        const int mt = w & 1;
        const int rh = w >> 1;
        const int arow = mt * 16 + col;
        const int ar = (arow < 21) ? arow : 20;            // clamped; rows masked at store

        float4 fqa = *(const float4*)(f2o + quad * 8);
        float4 fqb = *(const float4*)(f2o + quad * 8 + 4);
        float fq[8] = {fqa.x, fqa.y, fqa.z, fqa.w, fqb.x, fqb.y, fqb.z, fqb.w};
        float fi = f1o[ar];
        float ev[8];
        float ssum = 0.f;
        #pragma unroll
        for (int j = 0; j < 8; j++) {
            bool valid = (quad * 8 + j) < 21;
            float e = fi + fq[j]; e = (e >= 0.f) ? e : ALPHA * e;
            float x = __expf(e); x = valid ? x : 0.f;
            ev[j] = x; ssum += x;
        }
        ssum += __shfl_xor(ssum, 16); ssum += __shfl_xor(ssum, 32);
        float inv = 1.f / ssum;
        short8 a;
        #pragma unroll
        for (int j = 0; j < 8; j++) a[j] = hi16(ev[j] * inv);

        floatx4 acc[4];
        #pragma unroll
        for (int nt = 0; nt < 4; nt++) {
            short8 b = *(const short8*)(h2_t + (nt * 16 + col) * JPT + quad * 8);
            floatx4 z = {0,0,0,0};
            acc[nt] = __builtin_amdgcn_mfma_f32_16x16x32_bf16(a, b, z, 0, 0, 0);
        }
        float* outp = out + pair * (size_t)(J * HD);
        #pragma unroll
        for (int rr = 0; rr < 2; rr++) {
            int r = rh * 2 + rr;
            int row = mt * 16 + quad * 4 + r;
            float v0 = elu(acc[0][r]), v1 = elu(acc[1][r]);
            float v2 = elu(acc[2][r]), v3 = elu(acc[3][r]);
            float s = __expf(v0) + __expf(v1) + __expf(v2) + __expf(v3);
            s += __shfl_xor(s, 1);
            s += __shfl_xor(s, 2);
            s += __shfl_xor(s, 4);
            s += __shfl_xor(s, 8);
            float ls = __logf(s);
            if (row < J) {
                outp[row * HD +      col] = v0 - ls;
                outp[row * HD + 16 + col] = v1 - ls;
                outp[row * HD + 32 + col] = v2 - ls;
                outp[row * HD + 48 + col] = v3 - ls;
            }
        }
    }
}

extern "C" void kernel_launch(void* const* d_in, const int* in_sizes, int n_in,
                              void* d_out, int out_size, void* d_ws, size_t ws_size,
                              hipStream_t stream) {
    const float* inp = (const float*)d_in[0];
    // d_in[1] = seq_start_end (int64) — unused by the reference computation
    const float* Wh  = (const float*)d_in[2];
    const float* ah  = (const float*)d_in[3];
    const float* Wo  = (const float*)d_in[4];
    const float* ao  = (const float*)d_in[5];
    float* outp = (float*)d_out;
    short* ws   = (short*)d_ws;   // 18432 shorts + 64 floats = 37120 B

    hipLaunchKernelGGL(preconv, dim3(73), dim3(256), 0, stream, Wo, Wh, ah, ws);

    const int pairs = in_sizes[0] / (J * NH);  // 16384
    hipLaunchKernelGGL(gat_kernel, dim3(pairs), dim3(256), 0, stream,
                       inp, ao, (const short*)ws, outp);
}

// Round 12
// 218.874 us; speedup vs baseline: 1.1926x; 1.0516x over previous
//
#include <hip/hip_runtime.h>
#include <hip/hip_bf16.h>
#include <math.h>

// Problem constants
#define J   21
#define NH  7
#define H   4
#define HD  64
#define ALPHA 0.2f

// LDS strides (in elements)
#define HPS  264   // hp_bf row stride (shorts)
#define JPA  40    // x_bf row stride (shorts)
#define JPT  24    // h_t / h2_t row stride (shorts); j 21..23 zeroed; quad3 b128 reads overlap
                   // the next row (finite) — A-side k>=21 is exact zero so products vanish;
                   // the very last h_t row spills into the zeroed tail pad.
#define F12S 24    // f1/f2 per-head stride (floats)
#define ROW2 68    // h2 fp32 row stride (floats)

// LDS map (floats), total 6612 f = 26448 B  (<= 163840/6 -> 6 blocks/CU):
//   [0,2904)      hp_bf[22][HPS] shorts (s4 out / s5 A); xs_raw[147] overlay (s0/s1b);
//                 f1o@[0,21), f2o@[24,45) overlay post-s5 (s6 out / s8 in)
//   [2904,3344)   x_bf[22][JPA] shorts (s0 out / s1 A); dead after s1 — ALL 440 floats must be
//                 zeroed by the grid-stride loop (R11 NaN bug: if(t<440) covered only 256)
//   [3344,3536)   f1[4][F12S] @3344, f2[4][F12S] @3440 (s1b out / s4 softmax in)
//   [3536,6608)   h_t[256][JPT] shorts (s1 out / s4 B);
//                 post-s4 overlays: h2[21][ROW2] fp32 @3536 (s5 out / s6 in) ends 4959,
//                 h2_t[64][JPT] shorts @ float-off 4964 (s5 out / s8 B) ends 5732;
//                 [5732,6608) dead h_t leftovers (finite bf16; s8 quad3 spill lands here, zero-masked)
//   [6608,6612)   tail pad — zeroed in s0 (s4 quad3 spillover of last h_t row)
#define LDS_FLOATS 6612

typedef __attribute__((ext_vector_type(8))) short short8;
typedef __attribute__((ext_vector_type(4))) float floatx4;

static __device__ __forceinline__ short f2bf(float f) {          // RNE (preconv only)
    __hip_bfloat16 h = __float2bfloat16(f);
    return __builtin_bit_cast(short, h);
}
static __device__ __forceinline__ short hi16(float f) {          // truncating bf16 (cheap)
    return (short)(__builtin_bit_cast(unsigned, f) >> 16);
}
static __device__ __forceinline__ unsigned pack2hi(float lo, float hi) {
    return __builtin_amdgcn_perm(__builtin_bit_cast(unsigned, hi),
                                 __builtin_bit_cast(unsigned, lo), 0x07060302u);
}
static __device__ __forceinline__ float elu(float a) {
    return (a > 0.f) ? a : (__expf(a) - 1.f);
}

// ---- pre-kernel: bf16 weight tables + wha fusion ----
// ws shorts: [0,16384)      WoT[n=64][k=256] = bf(Wo[k][n])
//            [16384,18432)  WhT[(h*64+d)][8] : n<7 -> bf(Wh[h][n][d]), n=7 -> 0
//            [18432,18560)  wha[h][2][8] fp32 : wha[h][s][n] = sum_d Wh[h][n][d]*ah[h][s*64+d]
__global__ void preconv(const float* __restrict__ Wo, const float* __restrict__ Wh,
                        const float* __restrict__ ah, short* __restrict__ ws) {
    int t = blockIdx.x * 256 + threadIdx.x;
    if (t < 16384) {
        int n = t >> 8, k = t & 255;
        ws[t] = f2bf(Wo[k * HD + n]);
    } else if (t < 18432) {
        int i = t - 16384;
        int hh = i >> 9, d = (i >> 3) & 63, n = i & 7;
        ws[t] = (n < 7) ? f2bf(Wh[(hh * NH + n) * HD + d]) : (short)0;
    } else if (t < 18496) {
        int i = t - 18432;                 // 0..63
        int hh = i >> 4, s = (i >> 3) & 1, n = i & 7;
        float acc = 0.f;
        if (n < 7) {
            for (int d = 0; d < HD; d++)
                acc += Wh[(hh * NH + n) * HD + d] * ah[hh * 2 * HD + s * HD + d];
        }
        ((float*)(ws + 18432))[i] = acc;
    }
}

__global__ __launch_bounds__(256, 6)
void gat_kernel(const float* __restrict__ inp,
                const float* __restrict__ ao,   // (2*HD,)
                const short* __restrict__ ws,   // WoT + WhT + wha
                float* __restrict__ out)
{
    __shared__ __align__(16) float smem[LDS_FLOATS];
    short* hp_bf  = (short*)smem;                 // [22][HPS]
    float* f1o    = smem;                         // post-s5 overlays of hp region
    float* f2o    = smem + 24;
    float* f1     = smem + 3344;                  // [4][F12S]
    float* f2     = smem + 3440;
    short* h_t    = (short*)(smem + 3536);        // [256][JPT]
    float* h2     = smem + 3536;                  // [21][ROW2] fp32 (overlays dead h_t)
    short* h2_t   = (short*)(smem + 4964);        // [64][JPT] (overlays dead h_t)

    const short* WoT  = ws;
    const short* WhT  = ws + 16384;
    const float* whaF = (const float*)(ws + 18432);

    const int t    = threadIdx.x;
    const int w    = t >> 6;          // wave = head = tile index
    const int lane = t & 63;
    const int quad = lane >> 4;
    const int col  = lane & 15;
    const int rc   = (16 + col < 21) ? (16 + col) : 21;   // clamped M1 row (row 21 zeroed)

    const size_t pair = blockIdx.x;
    const float* ip = inp + pair * (size_t)(J * NH);

    // ---- stage 0: zero x_bf region (ALL 440 floats — grid-stride) + tail; scatter inputs ----
    for (int e = t; e < 440; e += 256) smem[2904 + e] = 0.f;
    if (t < 4) smem[6608 + t] = 0.f;   // tail pad: s4 quad3 B-read of last h_t row spills here
    __syncthreads();
    if (t < J * NH) {
        float v = ip[t];
        int j, k;
        if (t < 63)       { j = t / 3;        k = t % 3; }
        else if (t < 126) { j = (t - 63) / 3; k = 3 + (t - 63) % 3; }
        else              { j = t - 126;      k = 6; }
        ((short*)(smem + 2904))[j * JPA + k] = hi16(v);   // x_bf
        smem[t] = v;                                      // xs_raw (hp region, dead until s4)
    }
    __syncthreads();

    // ---- stage 1 (MFMA): h = x[21x7pad32] @ Wh_head[7x64] -> h_t bf16 (B-layout);
    //      1b: f1/f2 = x @ wha (fp32) ----
    {
        const short* x_bf = (const short*)(smem + 2904);
        short8 xa0 = *(const short8*)(x_bf + col * JPA + quad * 8);
        short8 xa1 = *(const short8*)(x_bf + rc  * JPA + quad * 8);
        #pragma unroll
        for (int nt = 0; nt < 4; nt++) {
            short8 b = *(const short8*)(WhT + ((w * 64 + nt * 16 + col) << 3) + quad * 8);
            floatx4 z = {0.f, 0.f, 0.f, 0.f};
            floatx4 c0 = __builtin_amdgcn_mfma_f32_16x16x32_bf16(xa0, b, z, 0, 0, 0);
            floatx4 c1 = __builtin_amdgcn_mfma_f32_16x16x32_bf16(xa1, b, z, 0, 0, 0);
            short* colbase = h_t + (w * 64 + nt * 16 + col) * JPT;
            #pragma unroll
            for (int r = 0; r < 4; r++) {
                colbase[quad * 4 + r] = hi16(c0[r]);
                int row1 = 16 + quad * 4 + r;
                if (row1 < J) colbase[row1] = hi16(c1[r]);
                else if (row1 < JPT) colbase[row1] = 0;
            }
        }
        if (t < 84) {
            int hh = t / 21, j = t - hh * 21;
            const float* xr = smem;    // xs_raw
            float x0 = xr[j*3+0], x1 = xr[j*3+1], x2 = xr[j*3+2];
            float x3 = xr[63+j*3+0], x4 = xr[63+j*3+1], x5 = xr[63+j*3+2];
            float x6 = xr[126+j];
            const float* wp = whaF + hh * 16;
            f1[hh * F12S + j] = x0*wp[0] + x1*wp[1] + x2*wp[2] + x3*wp[3]
                              + x4*wp[4] + x5*wp[5] + x6*wp[6];
            f2[hh * F12S + j] = x0*wp[8] + x1*wp[9] + x2*wp[10] + x3*wp[11]
                              + x4*wp[12] + x5*wp[13] + x6*wp[14];
        }
    }
    __syncthreads();

    // ---- stage 4 (MFMA + register softmax): lane builds its attn A-frag k-window
    //      [quad*8, quad*8+8) in registers; row denominators via cross-quad butterfly.
    //      Then hp = attn[21x21pad32] @ h[21x64], ELU -> hp_bf (A-layout); hp row 21 zeroed. ----
    {
        float4 fqa = *(const float4*)(f2 + w * F12S + quad * 8);
        float4 fqb = *(const float4*)(f2 + w * F12S + quad * 8 + 4);
        float fq[8] = {fqa.x, fqa.y, fqa.z, fqa.w, fqb.x, fqb.y, fqb.z, fqb.w};
        float fi0 = f1[w * F12S + col];
        const int am  = 16 + col;
        const int amc = (am < 21) ? am : 20;          // duplicate row 20; results masked
        float fi1 = f1[w * F12S + amc];
        float e0[8], e1[8];
        float s0 = 0.f, s1 = 0.f;
        #pragma unroll
        for (int j = 0; j < 8; j++) {
            bool valid = (quad * 8 + j) < 21;
            float a0 = fi0 + fq[j]; a0 = (a0 >= 0.f) ? a0 : ALPHA * a0;
            float a1 = fi1 + fq[j]; a1 = (a1 >= 0.f) ? a1 : ALPHA * a1;
            float x0 = __expf(a0); x0 = valid ? x0 : 0.f;   // no max pass: |e| bounded small
            float x1 = __expf(a1); x1 = valid ? x1 : 0.f;
            e0[j] = x0; e1[j] = x1; s0 += x0; s1 += x1;
        }
        s0 += __shfl_xor(s0, 16); s0 += __shfl_xor(s0, 32);
        s1 += __shfl_xor(s1, 16); s1 += __shfl_xor(s1, 32);
        float inv0 = 1.f / s0, inv1 = 1.f / s1;
        short8 aa0, aa1;
        #pragma unroll
        for (int j = 0; j < 8; j++) {
            aa0[j] = hi16(e0[j] * inv0);
            aa1[j] = hi16(e1[j] * inv1);
        }

        #pragma unroll
        for (int nt = 0; nt < 4; nt++) {
            short8 b = *(const short8*)(h_t + (w * 64 + nt * 16 + col) * JPT + quad * 8);
            floatx4 z = {0.f, 0.f, 0.f, 0.f};
            floatx4 c0 = __builtin_amdgcn_mfma_f32_16x16x32_bf16(aa0, b, z, 0, 0, 0);
            floatx4 c1 = __builtin_amdgcn_mfma_f32_16x16x32_bf16(aa1, b, z, 0, 0, 0);
            #pragma unroll
            for (int r = 0; r < 4; r++) {
                int row0 = quad * 4 + r;
                hp_bf[row0 * HPS + w * 64 + nt * 16 + col] = hi16(elu(c0[r]));
                int row1 = 16 + quad * 4 + r;
                if (row1 < J)
                    hp_bf[row1 * HPS + w * 64 + nt * 16 + col] = hi16(elu(c1[r]));
                else if (row1 == 21)
                    hp_bf[21 * HPS + w * 64 + nt * 16 + col] = 0;
            }
        }
    }
    __syncthreads();

    // ---- stage 5 (MFMA): h2 = hp[21x256] @ Wo[256x64] -> h2 fp32 (s6) AND h2_t bf16 (s8) ----
    {
        floatx4 d0 = {0,0,0,0}, d1 = {0,0,0,0};
        #pragma unroll
        for (int s = 0; s < 8; s++) {
            short8 a0 = *(const short8*)(hp_bf + col * HPS + s * 32 + quad * 8);
            short8 a1 = *(const short8*)(hp_bf + rc  * HPS + s * 32 + quad * 8);
            short8 b  = *(const short8*)(WoT + (w * 16 + col) * 256 + s * 32 + quad * 8);
            d0 = __builtin_amdgcn_mfma_f32_16x16x32_bf16(a0, b, d0, 0, 0, 0);
            d1 = __builtin_amdgcn_mfma_f32_16x16x32_bf16(a1, b, d1, 0, 0, 0);
        }
        const int c = w * 16 + col;
        #pragma unroll
        for (int r = 0; r < 4; r++) {
            h2[(quad * 4 + r) * ROW2 + c] = d0[r];
            int row1 = 16 + quad * 4 + r;
            if (row1 < J) h2[row1 * ROW2 + c] = d1[r];
        }
        short* cb = h2_t + c * JPT;
        *(uint2*)(cb + quad * 4) = make_uint2(pack2hi(d0[0], d0[1]), pack2hi(d0[2], d0[3]));
        if (quad == 0)
            *(uint2*)(cb + 16) = make_uint2(pack2hi(d1[0], d1[1]), pack2hi(d1[2], d1[3]));
        else if (quad == 1)
            *(uint2*)(cb + 20) = make_uint2(pack2hi(d1[0], 0.f), 0u);
    }
    __syncthreads();

    // ---- stage 6: f1o[j] = h2[j][:].ao[:64], f2o[j] = h2[j][:].ao[64:] ----
    if (t < 2 * J) {
        int which = t / J, j = t % J;
        const float4* hrow = (const float4*)(h2 + j * ROW2);
        const float4* ap   = (const float4*)(ao + which * HD);
        float sacc = 0.f;
        #pragma unroll
        for (int k = 0; k < HD / 4; k++) {
            float4 hv = hrow[k], av = ap[k];
            sacc += hv.x*av.x + hv.y*av.y + hv.z*av.z + hv.w*av.w;
        }
        if (which == 0) f1o[j] = sacc; else f2o[j] = sacc;
    }
    __syncthreads();

    // ---- stage 8 (MFMA + register softmax, barrier-free): lane builds attn2 A-frag
    //      window in registers (row ar), then hp2 = attn2[21x21pad32] @ h2[21x64],
    //      ELU, in-wave log-softmax, store ----
    {
        const int mt = w & 1;
        const int rh = w >> 1;
        const int arow = mt * 16 + col;
        const int ar = (arow < 21) ? arow : 20;            // clamped; rows masked at store

        float4 fqa = *(const float4*)(f2o + quad * 8);
        float4 fqb = *(const float4*)(f2o + quad * 8 + 4);
        float fq[8] = {fqa.x, fqa.y, fqa.z, fqa.w, fqb.x, fqb.y, fqb.z, fqb.w};
        float fi = f1o[ar];
        float ev[8];
        float ssum = 0.f;
        #pragma unroll
        for (int j = 0; j < 8; j++) {
            bool valid = (quad * 8 + j) < 21;
            float e = fi + fq[j]; e = (e >= 0.f) ? e : ALPHA * e;
            float x = __expf(e); x = valid ? x : 0.f;
            ev[j] = x; ssum += x;
        }
        ssum += __shfl_xor(ssum, 16); ssum += __shfl_xor(ssum, 32);
        float inv = 1.f / ssum;
        short8 a;
        #pragma unroll
        for (int j = 0; j < 8; j++) a[j] = hi16(ev[j] * inv);

        floatx4 acc[4];
        #pragma unroll
        for (int nt = 0; nt < 4; nt++) {
            short8 b = *(const short8*)(h2_t + (nt * 16 + col) * JPT + quad * 8);
            floatx4 z = {0,0,0,0};
            acc[nt] = __builtin_amdgcn_mfma_f32_16x16x32_bf16(a, b, z, 0, 0, 0);
        }
        float* outp = out + pair * (size_t)(J * HD);
        #pragma unroll
        for (int rr = 0; rr < 2; rr++) {
            int r = rh * 2 + rr;
            int row = mt * 16 + quad * 4 + r;
            float v0 = elu(acc[0][r]), v1 = elu(acc[1][r]);
            float v2 = elu(acc[2][r]), v3 = elu(acc[3][r]);
            float s = __expf(v0) + __expf(v1) + __expf(v2) + __expf(v3);
            s += __shfl_xor(s, 1);
            s += __shfl_xor(s, 2);
            s += __shfl_xor(s, 4);
            s += __shfl_xor(s, 8);
            float ls = __logf(s);
            if (row < J) {
                outp[row * HD +      col] = v0 - ls;
                outp[row * HD + 16 + col] = v1 - ls;
                outp[row * HD + 32 + col] = v2 - ls;
                outp[row * HD + 48 + col] = v3 - ls;
            }
        }
    }
}

extern "C" void kernel_launch(void* const* d_in, const int* in_sizes, int n_in,
                              void* d_out, int out_size, void* d_ws, size_t ws_size,
                              hipStream_t stream) {
    const float* inp = (const float*)d_in[0];
    // d_in[1] = seq_start_end (int64) — unused by the reference computation
    const float* Wh  = (const float*)d_in[2];
    const float* ah  = (const float*)d_in[3];
    const float* Wo  = (const float*)d_in[4];
    const float* ao  = (const float*)d_in[5];
    float* outp = (float*)d_out;
    short* ws   = (short*)d_ws;   // 18432 shorts + 64 floats = 37120 B

    hipLaunchKernelGGL(preconv, dim3(73), dim3(256), 0, stream, Wo, Wh, ah, ws);

    const int pairs = in_sizes[0] / (J * NH);  // 16384
    hipLaunchKernelGGL(gat_kernel, dim3(pairs), dim3(256), 0, stream,
                       inp, ao, (const short*)ws, outp);
}